// Round 1
// baseline (532.307 us; speedup 1.0000x reference)
//
#include <hip/hip_runtime.h>
#include <hip/hip_bf16.h>

#define M_LEN 1024
#define BATCH 16384

#define BM 128
#define BN 128
#define BK 64
#define THREADS 256

typedef __attribute__((ext_vector_type(8))) short bf16x8;
typedef __attribute__((ext_vector_type(4))) float f32x4;

// pack two fp32 -> two bf16 (RTZ truncation) in one v_perm_b32
__device__ __forceinline__ unsigned pack2(float lo, float hi) {
    return __builtin_amdgcn_perm(__float_as_uint(hi), __float_as_uint(lo), 0x07060302u);
}

// One fused kernel: scores GEMM (bf16 MFMA, modality-interleaved M), in-lane
// softmax over the 4 accumulator regs (C/D row = quad*4+reg => reg == modality),
// fp32 elementwise reweight, zero-modality rescale (OR-reduction over staged data).
__global__ __launch_bounds__(THREADS) void fused_modal_attn(
    const float* __restrict__ mod0, const float* __restrict__ mod1,
    const float* __restrict__ mod2, const float* __restrict__ mod3,
    const float* __restrict__ W, float* __restrict__ out)
{
    // LDS tiles: 128 rows x 64 bf16, rows of 8 x 16B chunks, chunk slot XOR-swizzled
    __shared__ __align__(16) unsigned short As[BM * BK];
    __shared__ __align__(16) unsigned short Bs[BN * BK];
    __shared__ unsigned rowOr[BM];
    __shared__ float scalerS[BM / 4];

    const int t    = threadIdx.x;
    const int lane = t & 63;
    const int wave = t >> 6;
    const int quad = lane >> 4;
    const int ln15 = lane & 15;
    const int wm   = wave >> 1;   // wave row 0..1 (64 rows each)
    const int wn   = wave & 1;    // wave col 0..1 (64 cols each)

    const int colb = blockIdx.x;      // 0..7   (output-column tile)
    const int rowb = blockIdx.y;      // 0..511 (A' row tile)
    const int row0 = rowb * BM;       // A' row base; A' row = 4*b + m
    const int col0 = colb * BN;

    if (t < BM) rowOr[t] = 0u;

    // staging map: chunk c = j*256 + t ; row r = c>>3 = j*32 + (t>>3); chunk-in-row = t&7
    const int sr  = t >> 3;
    const int scl = t & 7;

    const float* ap[4];
    const float* bp[4];
    unsigned ldsOff[4];               // short-index; same geometry for As and Bs
    unsigned orAcc[4] = {0u, 0u, 0u, 0u};
    #pragma unroll
    for (int j = 0; j < 4; ++j) {
        const int r  = j * 32 + sr;
        const int gr = row0 + r;                  // = 4*b + m
        const int b  = gr >> 2;
        const int m  = gr & 3;
        const float* mp = (m == 0) ? mod0 : (m == 1) ? mod1 : (m == 2) ? mod2 : mod3;
        ap[j] = mp + (size_t)b * M_LEN + scl * 8;
        bp[j] = W + (size_t)(col0 + r) * M_LEN + scl * 8;
        ldsOff[j] = (unsigned)(r * 64 + ((scl ^ (r & 7)) * 8));  // byte = r*128 + slot*16
    }

    f32x4 acc[4][4];
    #pragma unroll
    for (int i = 0; i < 4; ++i)
        #pragma unroll
        for (int j = 0; j < 4; ++j)
            acc[i][j] = (f32x4){0.f, 0.f, 0.f, 0.f};

    // frag read addressing: row = (wm|wn)*64 + i*16 + ln15, r&7 == ln15&7,
    // logical chunk = ks*4 + quad, physical slot = logical ^ (r&7)
    const unsigned slotB   = (unsigned)(quad ^ (ln15 & 7));
    const unsigned aRowOff = (unsigned)((wm * 64 + ln15) * 64);
    const unsigned bRowOff = (unsigned)((wn * 64 + ln15) * 64);

    for (int it = 0; it < 16; ++it) {
        __syncthreads();
        #pragma unroll
        for (int j = 0; j < 4; ++j) {
            const float4* pa = (const float4*)ap[j];
            const float4* pb = (const float4*)bp[j];
            float4 a0 = pa[0], a1 = pa[1];
            float4 b0 = pb[0], b1 = pb[1];
            ap[j] += BK; bp[j] += BK;

            unsigned pA0 = pack2(a0.x, a0.y), pA1 = pack2(a0.z, a0.w);
            unsigned pA2 = pack2(a1.x, a1.y), pA3 = pack2(a1.z, a1.w);
            orAcc[j] |= (pA0 | pA1) | (pA2 | pA3);
            *(uint4*)(&As[ldsOff[j]]) = make_uint4(pA0, pA1, pA2, pA3);

            unsigned pB0 = pack2(b0.x, b0.y), pB1 = pack2(b0.z, b0.w);
            unsigned pB2 = pack2(b1.x, b1.y), pB3 = pack2(b1.z, b1.w);
            *(uint4*)(&Bs[ldsOff[j]]) = make_uint4(pB0, pB1, pB2, pB3);
        }
        __syncthreads();
        #pragma unroll
        for (int ks = 0; ks < 2; ++ks) {
            const unsigned slot8 = (slotB ^ (unsigned)(ks * 4)) * 8u;
            bf16x8 af[4], bfr[4];
            #pragma unroll
            for (int i = 0; i < 4; ++i)
                af[i] = *(const bf16x8*)(&As[aRowOff + i * 1024 + slot8]);
            #pragma unroll
            for (int j = 0; j < 4; ++j)
                bfr[j] = *(const bf16x8*)(&Bs[bRowOff + j * 1024 + slot8]);
            #pragma unroll
            for (int i = 0; i < 4; ++i)
                #pragma unroll
                for (int j = 0; j < 4; ++j)
                    acc[i][j] = __builtin_amdgcn_mfma_f32_16x16x32_bf16(
                        af[i], bfr[j], acc[i][j], 0, 0, 0);
        }
    }

    // zero-modality detection: OR over everything this block staged (full rows)
    #pragma unroll
    for (int j = 0; j < 4; ++j)
        atomicOr(&rowOr[j * 32 + sr], orAcc[j]);
    __syncthreads();
    if (t < 32) {
        const int z = (rowOr[4 * t + 0] == 0u) + (rowOr[4 * t + 1] == 0u)
                    + (rowOr[4 * t + 2] == 0u) + (rowOr[4 * t + 3] == 0u);
        scalerS[t] = (z > 0) ? (float)(z + 1) : 1.0f;
    }
    __syncthreads();

    // epilogue: acc[i][j] components = scores of modalities 0..3 at one (b,k)
    #pragma unroll
    for (int i = 0; i < 4; ++i) {
        const int bl = wm * 16 + i * 4 + quad;   // local batch row (0..31)
        const int b  = rowb * 32 + bl;
        const float scal = scalerS[bl];
        #pragma unroll
        for (int j = 0; j < 4; ++j) {
            const int k = col0 + wn * 64 + j * 16 + ln15;
            const size_t off = (size_t)b * M_LEN + k;
            const float x0 = mod0[off], x1 = mod1[off];
            const float x2 = mod2[off], x3 = mod3[off];
            const f32x4 s = acc[i][j];
            const float mx = fmaxf(fmaxf(s.x, s.y), fmaxf(s.z, s.w));
            const float e0 = __expf(s.x - mx);
            const float e1 = __expf(s.y - mx);
            const float e2 = __expf(s.z - mx);
            const float e3 = __expf(s.w - mx);
            const float num = e0 * x0 + e1 * x1 + e2 * x2 + e3 * x3;
            out[off] = num * scal / (e0 + e1 + e2 + e3);
        }
    }
}

extern "C" void kernel_launch(void* const* d_in, const int* in_sizes, int n_in,
                              void* d_out, int out_size, void* d_ws, size_t ws_size,
                              hipStream_t stream) {
    const float* mod0 = (const float*)d_in[0];
    const float* mod1 = (const float*)d_in[1];
    const float* mod2 = (const float*)d_in[2];
    const float* mod3 = (const float*)d_in[3];
    const float* W    = (const float*)d_in[4];
    float* out = (float*)d_out;

    // grid: columns fastest -> 8 blocks sharing an A row-tile land on 8 XCDs
    // nearly simultaneously; L3 dedups the shared A fetch.
    dim3 grid(M_LEN / BN, (4 * BATCH) / BM);   // (8, 512)
    fused_modal_attn<<<grid, dim3(THREADS), 0, stream>>>(mod0, mod1, mod2, mod3, W, out);
}

// Round 2
// 498.986 us; speedup vs baseline: 1.0668x; 1.0668x over previous
//
#include <hip/hip_runtime.h>
#include <hip/hip_bf16.h>

#define M_LEN 1024
#define BATCH 16384

#define BM 128
#define BN 128
#define BK 64
#define THREADS 256

typedef __attribute__((ext_vector_type(8))) short bf16x8;
typedef __attribute__((ext_vector_type(4))) float f32x4;
typedef unsigned short ushort_t;

// ---------------- helpers ----------------

// fp32 -> bf16 RNE
__device__ __forceinline__ ushort_t bf16_rne(float f) {
    unsigned u = __float_as_uint(f);
    unsigned r = u + 0x7FFFu + ((u >> 16) & 1u);
    return (ushort_t)(r >> 16);
}

// pack two fp32 -> two bf16 (RTZ) in one v_perm_b32 (fallback kernel only)
__device__ __forceinline__ unsigned pack2(float lo, float hi) {
    return __builtin_amdgcn_perm(__float_as_uint(hi), __float_as_uint(lo), 0x07060302u);
}

// async global->LDS, 16B per lane. LDS dest is wave-uniform base + lane*16.
__device__ __forceinline__ void gload_lds16(const void* g, void* l) {
    __builtin_amdgcn_global_load_lds(
        (const __attribute__((address_space(1))) unsigned int*)g,
        (__attribute__((address_space(3))) unsigned int*)l,
        16, 0, 0);
}

// ---------------- pass 1: fp32 -> bf16 conversion + zero-row flags ----------------
// blocks 0..16383: block b, wave m converts mod_m row b -> Ab[(4b+m)*1024 ...]
//                  and writes zf[4b+m] = (row is all +-0.0) ? 1 : 0
// blocks 16384..16639: wave w converts W row (blk-16384)*4+w -> Wb
__global__ __launch_bounds__(THREADS) void convert_pass(
    const float* __restrict__ mod0, const float* __restrict__ mod1,
    const float* __restrict__ mod2, const float* __restrict__ mod3,
    const float* __restrict__ W,
    ushort_t* __restrict__ Ab, ushort_t* __restrict__ Wb, int* __restrict__ zf)
{
    const int blk  = blockIdx.x;
    const int wave = threadIdx.x >> 6;
    const int lane = threadIdx.x & 63;

    if (blk < BATCH) {
        const int b = blk, m = wave;
        const float* mp = (m == 0) ? mod0 : (m == 1) ? mod1 : (m == 2) ? mod2 : mod3;
        const float4* row = (const float4*)(mp + (size_t)b * M_LEN);
        ushort_t* dst = Ab + ((size_t)b * 4 + m) * M_LEN;
        unsigned orr = 0u;
        #pragma unroll
        for (int j = 0; j < 4; ++j) {
            float4 v = row[j * 64 + lane];
            orr |= (__float_as_uint(v.x) | __float_as_uint(v.y) |
                    __float_as_uint(v.z) | __float_as_uint(v.w)) << 1;  // drop signs
            ushort4 o;
            o.x = bf16_rne(v.x); o.y = bf16_rne(v.y);
            o.z = bf16_rne(v.z); o.w = bf16_rne(v.w);
            ((ushort4*)dst)[j * 64 + lane] = o;
        }
        const int nz = __any(orr != 0u);
        if (lane == 0) zf[b * 4 + m] = nz ? 0 : 1;
    } else {
        const int r = (blk - BATCH) * 4 + wave;
        const float4* row = (const float4*)(W + (size_t)r * M_LEN);
        ushort_t* dst = Wb + (size_t)r * M_LEN;
        #pragma unroll
        for (int j = 0; j < 4; ++j) {
            float4 v = row[j * 64 + lane];
            ushort4 o;
            o.x = bf16_rne(v.x); o.y = bf16_rne(v.y);
            o.z = bf16_rne(v.z); o.w = bf16_rne(v.w);
            ((ushort4*)dst)[j * 64 + lane] = o;
        }
    }
}

// ---------------- pass 2: bf16 MFMA GEMM + in-lane softmax epilogue ----------------
// A' rows are modality-interleaved (gr = 4b+m); with 16x16x32 C/D mapping
// row = quad*4 + reg, acc reg index == modality. Staging via global_load_lds
// with the XOR swizzle applied on the GLOBAL address (LDS side is fixed
// base + lane*16): LDS slot (r, sc) holds global chunk sc ^ (r&7).
__global__ __launch_bounds__(THREADS) void gemm_fused(
    const ushort_t* __restrict__ Ab, const ushort_t* __restrict__ Wb,
    const float* __restrict__ mod0, const float* __restrict__ mod1,
    const float* __restrict__ mod2, const float* __restrict__ mod3,
    const int* __restrict__ zf, float* __restrict__ out)
{
    __shared__ __align__(16) ushort_t As[BM * BK];   // 16 KB, rows of 8 x 16B slots
    __shared__ __align__(16) ushort_t Bs[BN * BK];   // 16 KB
    __shared__ float scalerS[BM / 4];

    const int t    = threadIdx.x;
    const int lane = t & 63;
    const int wave = t >> 6;
    const int quad = lane >> 4;
    const int ln15 = lane & 15;
    const int wm   = wave >> 1;
    const int wn   = wave & 1;

    const int colb = blockIdx.x;
    const int rowb = blockIdx.y;
    const int row0 = rowb * BM;
    const int col0 = colb * BN;

    // scaler from pass-1 flags (one int4 per local batch row)
    if (t < 32) {
        const int4 f = ((const int4*)zf)[rowb * 32 + t];
        const int z = f.x + f.y + f.z + f.w;
        scalerS[t] = (z > 0) ? (float)(z + 1) : 1.0f;
    }

    // staging addressing: lane covers row r = wave*32 + q*8 + (lane>>3),
    // physical LDS slot sc = lane&7, global chunk c = sc ^ (r&7) = (lane&7)^(lane>>3)
    const int rloc = (lane >> 3);
    const int c    = (lane & 7) ^ rloc;
    const ushort_t* aPtr[4];
    const ushort_t* bPtr[4];
    #pragma unroll
    for (int q = 0; q < 4; ++q) {
        const int r = wave * 32 + q * 8 + rloc;
        aPtr[q] = Ab + (size_t)(row0 + r) * M_LEN + c * 8;
        bPtr[q] = Wb + (size_t)(col0 + r) * M_LEN + c * 8;
    }

    f32x4 acc[4][4];
    #pragma unroll
    for (int i = 0; i < 4; ++i)
        #pragma unroll
        for (int j = 0; j < 4; ++j)
            acc[i][j] = (f32x4){0.f, 0.f, 0.f, 0.f};

    // frag read: row = (wm|wn)*64 + i*16 + ln15; physical slot = (ks*4+quad)^(ln15&7)
    const unsigned slotB   = (unsigned)(quad ^ (ln15 & 7));
    const unsigned aRowOff = (unsigned)((wm * 64 + ln15) * 64);
    const unsigned bRowOff = (unsigned)((wn * 64 + ln15) * 64);

    for (int kt = 0; kt < 16; ++kt) {
        #pragma unroll
        for (int q = 0; q < 4; ++q) {
            gload_lds16(aPtr[q], &As[(wave * 4 + q) * 512]);
            gload_lds16(bPtr[q], &Bs[(wave * 4 + q) * 512]);
            aPtr[q] += BK;
            bPtr[q] += BK;
        }
        __syncthreads();   // drains vmcnt -> LDS tiles ready
        #pragma unroll
        for (int ks = 0; ks < 2; ++ks) {
            const unsigned slot8 = (slotB ^ (unsigned)(ks * 4)) * 8u;
            bf16x8 af[4], bfr[4];
            #pragma unroll
            for (int i = 0; i < 4; ++i)
                af[i] = *(const bf16x8*)(&As[aRowOff + i * 1024 + slot8]);
            #pragma unroll
            for (int j = 0; j < 4; ++j)
                bfr[j] = *(const bf16x8*)(&Bs[bRowOff + j * 1024 + slot8]);
            #pragma unroll
            for (int i = 0; i < 4; ++i)
                #pragma unroll
                for (int j = 0; j < 4; ++j)
                    acc[i][j] = __builtin_amdgcn_mfma_f32_16x16x32_bf16(
                        af[i], bfr[j], acc[i][j], 0, 0, 0);
        }
        __syncthreads();   // protect LDS before next overwrite
    }

    // epilogue: acc[i][j] components = scores of modalities 0..3 at one (b,k)
    #pragma unroll
    for (int i = 0; i < 4; ++i) {
        const int bl = wm * 16 + i * 4 + quad;
        const int b  = rowb * 32 + bl;
        const float scal = scalerS[bl];
        #pragma unroll
        for (int j = 0; j < 4; ++j) {
            const int k = col0 + wn * 64 + j * 16 + ln15;
            const size_t off = (size_t)b * M_LEN + k;
            const float x0 = mod0[off], x1 = mod1[off];
            const float x2 = mod2[off], x3 = mod3[off];
            const f32x4 s = acc[i][j];
            const float mx = fmaxf(fmaxf(s.x, s.y), fmaxf(s.z, s.w));
            const float e0 = __expf(s.x - mx);
            const float e1 = __expf(s.y - mx);
            const float e2 = __expf(s.z - mx);
            const float e3 = __expf(s.w - mx);
            const float num = e0 * x0 + e1 * x1 + e2 * x2 + e3 * x3;
            out[off] = num * scal / (e0 + e1 + e2 + e3);
        }
    }
}

// ---------------- fallback: round-1 single fused kernel (used if ws too small) ----
__global__ __launch_bounds__(THREADS) void fused_modal_attn(
    const float* __restrict__ mod0, const float* __restrict__ mod1,
    const float* __restrict__ mod2, const float* __restrict__ mod3,
    const float* __restrict__ W, float* __restrict__ out)
{
    __shared__ __align__(16) unsigned short As[BM * BK];
    __shared__ __align__(16) unsigned short Bs[BN * BK];
    __shared__ unsigned rowOr[BM];
    __shared__ float scalerS[BM / 4];

    const int t    = threadIdx.x;
    const int lane = t & 63;
    const int wave = t >> 6;
    const int quad = lane >> 4;
    const int ln15 = lane & 15;
    const int wm   = wave >> 1;
    const int wn   = wave & 1;

    const int colb = blockIdx.x;
    const int rowb = blockIdx.y;
    const int row0 = rowb * BM;
    const int col0 = colb * BN;

    if (t < BM) rowOr[t] = 0u;

    const int sr  = t >> 3;
    const int scl = t & 7;

    const float* ap[4];
    const float* bp[4];
    unsigned ldsOff[4];
    unsigned orAcc[4] = {0u, 0u, 0u, 0u};
    #pragma unroll
    for (int j = 0; j < 4; ++j) {
        const int r  = j * 32 + sr;
        const int gr = row0 + r;
        const int b  = gr >> 2;
        const int m  = gr & 3;
        const float* mp = (m == 0) ? mod0 : (m == 1) ? mod1 : (m == 2) ? mod2 : mod3;
        ap[j] = mp + (size_t)b * M_LEN + scl * 8;
        bp[j] = W + (size_t)(col0 + r) * M_LEN + scl * 8;
        ldsOff[j] = (unsigned)(r * 64 + ((scl ^ (r & 7)) * 8));
    }

    f32x4 acc[4][4];
    #pragma unroll
    for (int i = 0; i < 4; ++i)
        #pragma unroll
        for (int j = 0; j < 4; ++j)
            acc[i][j] = (f32x4){0.f, 0.f, 0.f, 0.f};

    const unsigned slotB   = (unsigned)(quad ^ (ln15 & 7));
    const unsigned aRowOff = (unsigned)((wm * 64 + ln15) * 64);
    const unsigned bRowOff = (unsigned)((wn * 64 + ln15) * 64);

    for (int it = 0; it < 16; ++it) {
        __syncthreads();
        #pragma unroll
        for (int j = 0; j < 4; ++j) {
            const float4* pa = (const float4*)ap[j];
            const float4* pb = (const float4*)bp[j];
            float4 a0 = pa[0], a1 = pa[1];
            float4 b0 = pb[0], b1 = pb[1];
            ap[j] += BK; bp[j] += BK;

            unsigned pA0 = pack2(a0.x, a0.y), pA1 = pack2(a0.z, a0.w);
            unsigned pA2 = pack2(a1.x, a1.y), pA3 = pack2(a1.z, a1.w);
            orAcc[j] |= (pA0 | pA1) | (pA2 | pA3);
            *(uint4*)(&As[ldsOff[j]]) = make_uint4(pA0, pA1, pA2, pA3);

            unsigned pB0 = pack2(b0.x, b0.y), pB1 = pack2(b0.z, b0.w);
            unsigned pB2 = pack2(b1.x, b1.y), pB3 = pack2(b1.z, b1.w);
            *(uint4*)(&Bs[ldsOff[j]]) = make_uint4(pB0, pB1, pB2, pB3);
        }
        __syncthreads();
        #pragma unroll
        for (int ks = 0; ks < 2; ++ks) {
            const unsigned slot8 = (slotB ^ (unsigned)(ks * 4)) * 8u;
            bf16x8 af[4], bfr[4];
            #pragma unroll
            for (int i = 0; i < 4; ++i)
                af[i] = *(const bf16x8*)(&As[aRowOff + i * 1024 + slot8]);
            #pragma unroll
            for (int j = 0; j < 4; ++j)
                bfr[j] = *(const bf16x8*)(&Bs[bRowOff + j * 1024 + slot8]);
            #pragma unroll
            for (int i = 0; i < 4; ++i)
                #pragma unroll
                for (int j = 0; j < 4; ++j)
                    acc[i][j] = __builtin_amdgcn_mfma_f32_16x16x32_bf16(
                        af[i], bfr[j], acc[i][j], 0, 0, 0);
        }
    }

    #pragma unroll
    for (int j = 0; j < 4; ++j)
        atomicOr(&rowOr[j * 32 + sr], orAcc[j]);
    __syncthreads();
    if (t < 32) {
        const int z = (rowOr[4 * t + 0] == 0u) + (rowOr[4 * t + 1] == 0u)
                    + (rowOr[4 * t + 2] == 0u) + (rowOr[4 * t + 3] == 0u);
        scalerS[t] = (z > 0) ? (float)(z + 1) : 1.0f;
    }
    __syncthreads();

    #pragma unroll
    for (int i = 0; i < 4; ++i) {
        const int bl = wm * 16 + i * 4 + quad;
        const int b  = rowb * 32 + bl;
        const float scal = scalerS[bl];
        #pragma unroll
        for (int j = 0; j < 4; ++j) {
            const int k = col0 + wn * 64 + j * 16 + ln15;
            const size_t off = (size_t)b * M_LEN + k;
            const float x0 = mod0[off], x1 = mod1[off];
            const float x2 = mod2[off], x3 = mod3[off];
            const f32x4 s = acc[i][j];
            const float mx = fmaxf(fmaxf(s.x, s.y), fmaxf(s.z, s.w));
            const float e0 = __expf(s.x - mx);
            const float e1 = __expf(s.y - mx);
            const float e2 = __expf(s.z - mx);
            const float e3 = __expf(s.w - mx);
            const float num = e0 * x0 + e1 * x1 + e2 * x2 + e3 * x3;
            out[off] = num * scal / (e0 + e1 + e2 + e3);
        }
    }
}

// ---------------- launch ----------------
extern "C" void kernel_launch(void* const* d_in, const int* in_sizes, int n_in,
                              void* d_out, int out_size, void* d_ws, size_t ws_size,
                              hipStream_t stream) {
    const float* mod0 = (const float*)d_in[0];
    const float* mod1 = (const float*)d_in[1];
    const float* mod2 = (const float*)d_in[2];
    const float* mod3 = (const float*)d_in[3];
    const float* W    = (const float*)d_in[4];
    float* out = (float*)d_out;

    // workspace layout: A' bf16 (128 MiB) | W bf16 (2 MiB) | zf int[65536] (256 KiB)
    const size_t abBytes = (size_t)4 * BATCH * M_LEN * sizeof(ushort_t);  // 134217728
    const size_t wbBytes = (size_t)M_LEN * M_LEN * sizeof(ushort_t);      //   2097152
    const size_t zfBytes = (size_t)4 * BATCH * sizeof(int);               //    262144
    const size_t need = abBytes + wbBytes + zfBytes;

    if (ws_size >= need) {
        ushort_t* Ab = (ushort_t*)d_ws;
        ushort_t* Wb = (ushort_t*)((char*)d_ws + abBytes);
        int*      zfp = (int*)((char*)d_ws + abBytes + wbBytes);

        convert_pass<<<dim3(BATCH + M_LEN / 4), dim3(THREADS), 0, stream>>>(
            mod0, mod1, mod2, mod3, W, Ab, Wb, zfp);

        dim3 grid(M_LEN / BN, (4 * BATCH) / BM);   // (8, 512), col-fastest
        gemm_fused<<<grid, dim3(THREADS), 0, stream>>>(
            Ab, Wb, mod0, mod1, mod2, mod3, zfp, out);
    } else {
        dim3 grid(M_LEN / BN, (4 * BATCH) / BM);
        fused_modal_attn<<<grid, dim3(THREADS), 0, stream>>>(
            mod0, mod1, mod2, mod3, W, out);
    }
}

// Round 4
// 408.785 us; speedup vs baseline: 1.3022x; 1.2207x over previous
//
#include <hip/hip_runtime.h>
#include <hip/hip_bf16.h>

#define M_LEN 1024
#define BATCH 16384

#define BM 128
#define BN 128
#define BK 64
#define THREADS 256

typedef __attribute__((ext_vector_type(8))) short bf16x8;
typedef __attribute__((ext_vector_type(4))) float f32x4;
typedef unsigned short ushort_t;

// ---------------- helpers ----------------

// fp32 -> bf16 RNE
__device__ __forceinline__ ushort_t bf16_rne(float f) {
    unsigned u = __float_as_uint(f);
    unsigned r = u + 0x7FFFu + ((u >> 16) & 1u);
    return (ushort_t)(r >> 16);
}

__device__ __forceinline__ float bf16_to_f(ushort_t u) {
    return __uint_as_float(((unsigned)u) << 16);
}

// pack two fp32 -> two bf16 (RTZ) in one v_perm_b32 (fallback kernel only)
__device__ __forceinline__ unsigned pack2(float lo, float hi) {
    return __builtin_amdgcn_perm(__float_as_uint(hi), __float_as_uint(lo), 0x07060302u);
}

// async global->LDS, 16B per lane. LDS dest is wave-uniform base + lane*16.
__device__ __forceinline__ void gload_lds16(const void* g, void* l) {
    __builtin_amdgcn_global_load_lds(
        (const __attribute__((address_space(1))) unsigned int*)g,
        (__attribute__((address_space(3))) unsigned int*)l,
        16, 0, 0);
}

// non-temporal 16B load: builtin requires native ext_vector_type, not HIP structs
__device__ __forceinline__ float4 ntload4(const float4* p) {
    f32x4 v = __builtin_nontemporal_load((const f32x4*)p);
    return make_float4(v.x, v.y, v.z, v.w);
}

// ---------------- pass 1: fp32 -> bf16 conversion + zero-row flags ----------------
// blocks 0..16383: block b, wave m converts mod_m row b -> Ab[(4b+m)*1024 ...]
//                  and writes zf[4b+m] = (row is all +-0.0) ? 1 : 0
// blocks 16384..16639: wave w converts W row (blk-16384)*4+w -> Wb
// mod reads are NON-TEMPORAL: they are read exactly once in the whole pipeline
// (epilogue uses Ab), so keep them out of L3 to preserve Ab residency.
__global__ __launch_bounds__(THREADS) void convert_pass(
    const float* __restrict__ mod0, const float* __restrict__ mod1,
    const float* __restrict__ mod2, const float* __restrict__ mod3,
    const float* __restrict__ W,
    ushort_t* __restrict__ Ab, ushort_t* __restrict__ Wb, int* __restrict__ zf)
{
    const int blk  = blockIdx.x;
    const int wave = threadIdx.x >> 6;
    const int lane = threadIdx.x & 63;

    if (blk < BATCH) {
        const int b = blk, m = wave;
        const float* mp = (m == 0) ? mod0 : (m == 1) ? mod1 : (m == 2) ? mod2 : mod3;
        const float4* row = (const float4*)(mp + (size_t)b * M_LEN);
        ushort_t* dst = Ab + ((size_t)b * 4 + m) * M_LEN;
        unsigned orr = 0u;
        #pragma unroll
        for (int j = 0; j < 4; ++j) {
            float4 v = ntload4(&row[j * 64 + lane]);
            orr |= (__float_as_uint(v.x) | __float_as_uint(v.y) |
                    __float_as_uint(v.z) | __float_as_uint(v.w)) << 1;  // drop signs
            ushort4 o;
            o.x = bf16_rne(v.x); o.y = bf16_rne(v.y);
            o.z = bf16_rne(v.z); o.w = bf16_rne(v.w);
            ((ushort4*)dst)[j * 64 + lane] = o;
        }
        const int nz = __any(orr != 0u);
        if (lane == 0) zf[b * 4 + m] = nz ? 0 : 1;
    } else {
        const int r = (blk - BATCH) * 4 + wave;
        const float4* row = (const float4*)(W + (size_t)r * M_LEN);
        ushort_t* dst = Wb + (size_t)r * M_LEN;
        #pragma unroll
        for (int j = 0; j < 4; ++j) {
            float4 v = row[j * 64 + lane];
            ushort4 o;
            o.x = bf16_rne(v.x); o.y = bf16_rne(v.y);
            o.z = bf16_rne(v.z); o.w = bf16_rne(v.w);
            ((ushort4*)dst)[j * 64 + lane] = o;
        }
    }
}

// ---------------- pass 2: bf16 MFMA GEMM + in-lane softmax epilogue ----------------
// A' rows are modality-interleaved (gr = 4b+m); with 16x16x32 C/D mapping
// row = quad*4 + reg, acc reg index == modality. Staging via global_load_lds,
// XOR swizzle applied on the GLOBAL address (LDS side is fixed base+lane*16).
// Epilogue reads x as bf16 from Ab (L3-resident: A'+W = 130 MB < 256 MB L3)
// and stores out NON-TEMPORALLY so the output stream never evicts A'.
__global__ __launch_bounds__(THREADS) void gemm_fused(
    const ushort_t* __restrict__ Ab, const ushort_t* __restrict__ Wb,
    const int* __restrict__ zf, float* __restrict__ out)
{
    __shared__ __align__(16) ushort_t As[BM * BK];   // 16 KB, rows of 8 x 16B slots
    __shared__ __align__(16) ushort_t Bs[BN * BK];   // 16 KB
    __shared__ float scalerS[BM / 4];

    const int t    = threadIdx.x;
    const int lane = t & 63;
    const int wave = t >> 6;
    const int quad = lane >> 4;
    const int ln15 = lane & 15;
    const int wm   = wave >> 1;
    const int wn   = wave & 1;

    const int colb = blockIdx.x;
    const int rowb = blockIdx.y;
    const int row0 = rowb * BM;
    const int col0 = colb * BN;

    if (t < 32) {
        const int4 f = ((const int4*)zf)[rowb * 32 + t];
        const int z = f.x + f.y + f.z + f.w;
        scalerS[t] = (z > 0) ? (float)(z + 1) : 1.0f;
    }

    // staging: lane covers row r = wave*32 + q*8 + (lane>>3),
    // physical LDS slot = lane&7, global chunk = (lane&7)^(r&7)
    const int rloc = (lane >> 3);
    const int c    = (lane & 7) ^ rloc;
    const ushort_t* aPtr[4];
    const ushort_t* bPtr[4];
    #pragma unroll
    for (int q = 0; q < 4; ++q) {
        const int r = wave * 32 + q * 8 + rloc;
        aPtr[q] = Ab + (size_t)(row0 + r) * M_LEN + c * 8;
        bPtr[q] = Wb + (size_t)(col0 + r) * M_LEN + c * 8;
    }

    f32x4 acc[4][4];
    #pragma unroll
    for (int i = 0; i < 4; ++i)
        #pragma unroll
        for (int j = 0; j < 4; ++j)
            acc[i][j] = (f32x4){0.f, 0.f, 0.f, 0.f};

    const unsigned slotB   = (unsigned)(quad ^ (ln15 & 7));
    const unsigned aRowOff = (unsigned)((wm * 64 + ln15) * 64);
    const unsigned bRowOff = (unsigned)((wn * 64 + ln15) * 64);

    for (int kt = 0; kt < 16; ++kt) {
        #pragma unroll
        for (int q = 0; q < 4; ++q) {
            gload_lds16(aPtr[q], &As[(wave * 4 + q) * 512]);
            gload_lds16(bPtr[q], &Bs[(wave * 4 + q) * 512]);
            aPtr[q] += BK;
            bPtr[q] += BK;
        }
        __syncthreads();
        #pragma unroll
        for (int ks = 0; ks < 2; ++ks) {
            const unsigned slot8 = (slotB ^ (unsigned)(ks * 4)) * 8u;
            bf16x8 af[4], bfr[4];
            #pragma unroll
            for (int i = 0; i < 4; ++i)
                af[i] = *(const bf16x8*)(&As[aRowOff + i * 1024 + slot8]);
            #pragma unroll
            for (int j = 0; j < 4; ++j)
                bfr[j] = *(const bf16x8*)(&Bs[bRowOff + j * 1024 + slot8]);
            #pragma unroll
            for (int i = 0; i < 4; ++i)
                #pragma unroll
                for (int j = 0; j < 4; ++j)
                    acc[i][j] = __builtin_amdgcn_mfma_f32_16x16x32_bf16(
                        af[i], bfr[j], acc[i][j], 0, 0, 0);
        }
        __syncthreads();
    }

    // epilogue: acc[i][j] components = scores of modalities 0..3 at one (b,k).
    // x comes from Ab (bf16, same values the GEMM used) — L2/L3 hits, no HBM.
    #pragma unroll
    for (int i = 0; i < 4; ++i) {
        const int bl = wm * 16 + i * 4 + quad;
        const int b  = rowb * 32 + bl;
        const float scal = scalerS[bl];
        const ushort_t* xr = Ab + (size_t)b * 4 * M_LEN;   // row 4b (modality 0)
        #pragma unroll
        for (int j = 0; j < 4; ++j) {
            const int k = col0 + wn * 64 + j * 16 + ln15;
            const float x0 = bf16_to_f(xr[k]);
            const float x1 = bf16_to_f(xr[M_LEN + k]);
            const float x2 = bf16_to_f(xr[2 * M_LEN + k]);
            const float x3 = bf16_to_f(xr[3 * M_LEN + k]);
            const f32x4 s = acc[i][j];
            const float mx = fmaxf(fmaxf(s.x, s.y), fmaxf(s.z, s.w));
            const float e0 = __expf(s.x - mx);
            const float e1 = __expf(s.y - mx);
            const float e2 = __expf(s.z - mx);
            const float e3 = __expf(s.w - mx);
            const float num = e0 * x0 + e1 * x1 + e2 * x2 + e3 * x3;
            const float v = num * scal / (e0 + e1 + e2 + e3);
            __builtin_nontemporal_store(v, &out[(size_t)b * M_LEN + k]);
        }
    }
}

// ---------------- fallback: round-1 single fused kernel (used if ws too small) ----
__global__ __launch_bounds__(THREADS) void fused_modal_attn(
    const float* __restrict__ mod0, const float* __restrict__ mod1,
    const float* __restrict__ mod2, const float* __restrict__ mod3,
    const float* __restrict__ W, float* __restrict__ out)
{
    __shared__ __align__(16) unsigned short As[BM * BK];
    __shared__ __align__(16) unsigned short Bs[BN * BK];
    __shared__ unsigned rowOr[BM];
    __shared__ float scalerS[BM / 4];

    const int t    = threadIdx.x;
    const int lane = t & 63;
    const int wave = t >> 6;
    const int quad = lane >> 4;
    const int ln15 = lane & 15;
    const int wm   = wave >> 1;
    const int wn   = wave & 1;

    const int colb = blockIdx.x;
    const int rowb = blockIdx.y;
    const int row0 = rowb * BM;
    const int col0 = colb * BN;

    if (t < BM) rowOr[t] = 0u;

    const int sr  = t >> 3;
    const int scl = t & 7;

    const float* ap[4];
    const float* bp[4];
    unsigned ldsOff[4];
    unsigned orAcc[4] = {0u, 0u, 0u, 0u};
    #pragma unroll
    for (int j = 0; j < 4; ++j) {
        const int r  = j * 32 + sr;
        const int gr = row0 + r;
        const int b  = gr >> 2;
        const int m  = gr & 3;
        const float* mp = (m == 0) ? mod0 : (m == 1) ? mod1 : (m == 2) ? mod2 : mod3;
        ap[j] = mp + (size_t)b * M_LEN + scl * 8;
        bp[j] = W + (size_t)(col0 + r) * M_LEN + scl * 8;
        ldsOff[j] = (unsigned)(r * 64 + ((scl ^ (r & 7)) * 8));
    }

    f32x4 acc[4][4];
    #pragma unroll
    for (int i = 0; i < 4; ++i)
        #pragma unroll
        for (int j = 0; j < 4; ++j)
            acc[i][j] = (f32x4){0.f, 0.f, 0.f, 0.f};

    const unsigned slotB   = (unsigned)(quad ^ (ln15 & 7));
    const unsigned aRowOff = (unsigned)((wm * 64 + ln15) * 64);
    const unsigned bRowOff = (unsigned)((wn * 64 + ln15) * 64);

    for (int it = 0; it < 16; ++it) {
        __syncthreads();
        #pragma unroll
        for (int j = 0; j < 4; ++j) {
            const float4* pa = (const float4*)ap[j];
            const float4* pb = (const float4*)bp[j];
            float4 a0 = pa[0], a1 = pa[1];
            float4 b0 = pb[0], b1 = pb[1];
            ap[j] += BK; bp[j] += BK;

            unsigned pA0 = pack2(a0.x, a0.y), pA1 = pack2(a0.z, a0.w);
            unsigned pA2 = pack2(a1.x, a1.y), pA3 = pack2(a1.z, a1.w);
            orAcc[j] |= (pA0 | pA1) | (pA2 | pA3);
            *(uint4*)(&As[ldsOff[j]]) = make_uint4(pA0, pA1, pA2, pA3);

            unsigned pB0 = pack2(b0.x, b0.y), pB1 = pack2(b0.z, b0.w);
            unsigned pB2 = pack2(b1.x, b1.y), pB3 = pack2(b1.z, b1.w);
            *(uint4*)(&Bs[ldsOff[j]]) = make_uint4(pB0, pB1, pB2, pB3);
        }
        __syncthreads();
        #pragma unroll
        for (int ks = 0; ks < 2; ++ks) {
            const unsigned slot8 = (slotB ^ (unsigned)(ks * 4)) * 8u;
            bf16x8 af[4], bfr[4];
            #pragma unroll
            for (int i = 0; i < 4; ++i)
                af[i] = *(const bf16x8*)(&As[aRowOff + i * 1024 + slot8]);
            #pragma unroll
            for (int j = 0; j < 4; ++j)
                bfr[j] = *(const bf16x8*)(&Bs[bRowOff + j * 1024 + slot8]);
            #pragma unroll
            for (int i = 0; i < 4; ++i)
                #pragma unroll
                for (int j = 0; j < 4; ++j)
                    acc[i][j] = __builtin_amdgcn_mfma_f32_16x16x32_bf16(
                        af[i], bfr[j], acc[i][j], 0, 0, 0);
        }
    }

    #pragma unroll
    for (int j = 0; j < 4; ++j)
        atomicOr(&rowOr[j * 32 + sr], orAcc[j]);
    __syncthreads();
    if (t < 32) {
        const int z = (rowOr[4 * t + 0] == 0u) + (rowOr[4 * t + 1] == 0u)
                    + (rowOr[4 * t + 2] == 0u) + (rowOr[4 * t + 3] == 0u);
        scalerS[t] = (z > 0) ? (float)(z + 1) : 1.0f;
    }
    __syncthreads();

    #pragma unroll
    for (int i = 0; i < 4; ++i) {
        const int bl = wm * 16 + i * 4 + quad;
        const int b  = rowb * 32 + bl;
        const float scal = scalerS[bl];
        #pragma unroll
        for (int j = 0; j < 4; ++j) {
            const int k = col0 + wn * 64 + j * 16 + ln15;
            const size_t off = (size_t)b * M_LEN + k;
            const float x0 = mod0[off], x1 = mod1[off];
            const float x2 = mod2[off], x3 = mod3[off];
            const f32x4 s = acc[i][j];
            const float mx = fmaxf(fmaxf(s.x, s.y), fmaxf(s.z, s.w));
            const float e0 = __expf(s.x - mx);
            const float e1 = __expf(s.y - mx);
            const float e2 = __expf(s.z - mx);
            const float e3 = __expf(s.w - mx);
            const float num = e0 * x0 + e1 * x1 + e2 * x2 + e3 * x3;
            out[off] = num * scal / (e0 + e1 + e2 + e3);
        }
    }
}

// ---------------- launch ----------------
extern "C" void kernel_launch(void* const* d_in, const int* in_sizes, int n_in,
                              void* d_out, int out_size, void* d_ws, size_t ws_size,
                              hipStream_t stream) {
    const float* mod0 = (const float*)d_in[0];
    const float* mod1 = (const float*)d_in[1];
    const float* mod2 = (const float*)d_in[2];
    const float* mod3 = (const float*)d_in[3];
    const float* W    = (const float*)d_in[4];
    float* out = (float*)d_out;

    // workspace layout: A' bf16 (128 MiB) | W bf16 (2 MiB) | zf int[65536] (256 KiB)
    const size_t abBytes = (size_t)4 * BATCH * M_LEN * sizeof(ushort_t);
    const size_t wbBytes = (size_t)M_LEN * M_LEN * sizeof(ushort_t);
    const size_t zfBytes = (size_t)4 * BATCH * sizeof(int);
    const size_t need = abBytes + wbBytes + zfBytes;

    if (ws_size >= need) {
        ushort_t* Ab = (ushort_t*)d_ws;
        ushort_t* Wb = (ushort_t*)((char*)d_ws + abBytes);
        int*      zfp = (int*)((char*)d_ws + abBytes + wbBytes);

        convert_pass<<<dim3(BATCH + M_LEN / 4), dim3(THREADS), 0, stream>>>(
            mod0, mod1, mod2, mod3, W, Ab, Wb, zfp);

        dim3 grid(M_LEN / BN, (4 * BATCH) / BM);   // (8, 512), col-fastest
        gemm_fused<<<grid, dim3(THREADS), 0, stream>>>(Ab, Wb, zfp, out);
    } else {
        dim3 grid(M_LEN / BN, (4 * BATCH) / BM);
        fused_modal_attn<<<grid, dim3(THREADS), 0, stream>>>(
            mod0, mod1, mod2, mod3, W, out);
    }
}